// Round 2
// baseline (435.038 us; speedup 1.0000x reference)
//
#include <hip/hip_runtime.h>
#include <math.h>

#define BATCH 4096
#define DIN   2048
#define DOUT  2048
#define DEPTH 16

typedef unsigned short u16;
typedef __attribute__((ext_vector_type(8))) short short8;  // 8 bf16 = 4 VGPRs (guide §3)
typedef __attribute__((ext_vector_type(4))) float f32x4;

// ---------- helpers ----------

__device__ static inline unsigned bf16_rn(float x) {
    unsigned u = __float_as_uint(x);
    return (u + 0x7FFFu + ((u >> 16) & 1u)) >> 16;  // RN-even to bf16 bits
}

__device__ static inline float tanh_fast(float z) {
    float zc = fminf(fmaxf(z, -15.0f), 15.0f);
    float e = __builtin_amdgcn_exp2f(zc * 2.8853900817779268f);  // exp(2z)
    return (e - 1.0f) * __builtin_amdgcn_rcpf(e + 1.0f);
}

__device__ static inline void async16(u16* lds, const u16* g) {
    __builtin_amdgcn_global_load_lds(
        (const __attribute__((address_space(1))) void*)g,
        (__attribute__((address_space(3))) void*)lds, 16, 0, 0);
}

// ---------- probs: probs[j] = (prod cos(W[d,j,g]))^2 / DIN ----------
// d-parallel: 16 lanes per j, shfl product-reduce. 128 blocks x 256 thr.
__global__ __launch_bounds__(256) void probs_kernel(const float* __restrict__ W,
                                                    float* __restrict__ probs) {
    int tid = threadIdx.x;
    int jl = tid >> 4, d = tid & 15;
    int j = blockIdx.x * 16 + jl;
    const float* p = W + (size_t)d * DIN * DOUT + (size_t)j * DOUT;
    float pr = cosf(p[0]) * cosf(p[1]) * cosf(p[2]);
#pragma unroll
    for (int off = 1; off < 16; off <<= 1) pr *= __shfl_xor(pr, off, 16);
    if (d == 0) probs[j] = pr * pr * (1.0f / (float)DIN);
}

// ---------- x -> hi/lo bf16 (RN split) ----------
__global__ __launch_bounds__(256) void convert_x_kernel(const float* __restrict__ x,
                                                        u16* __restrict__ xh,
                                                        u16* __restrict__ xl) {
    int i = (blockIdx.x * 256 + threadIdx.x) * 4;
    float4 v = *(const float4*)(x + i);
    ushort4 h, l;
    float vv[4] = {v.x, v.y, v.z, v.w};
    u16 hh[4], ll[4];
#pragma unroll
    for (int c = 0; c < 4; ++c) {
        unsigned hb = bf16_rn(vv[c]);
        hh[c] = (u16)hb;
        float r = vv[c] - __uint_as_float(hb << 16);
        ll[c] = (u16)bf16_rn(r);
    }
    h.x = hh[0]; h.y = hh[1]; h.z = hh[2]; h.w = hh[3];
    l.x = ll[0]; l.y = ll[1]; l.z = ll[2]; l.w = ll[3];
    *(ushort4*)(xh + i) = h;
    *(ushort4*)(xl + i) = l;
}

// ---------- W[k][n] -> Wt_hi/Wt_lo[n][k] (transpose + RN split) ----------
__global__ __launch_bounds__(256) void transpose_w_kernel(const float* __restrict__ W,
                                                          u16* __restrict__ wh,
                                                          u16* __restrict__ wl) {
    __shared__ float t[32][33];
    int n0 = blockIdx.x * 32, k0 = blockIdx.y * 32;
    int tx = threadIdx.x & 31, ty = threadIdx.x >> 5;  // ty 0..7
#pragma unroll
    for (int i = 0; i < 4; ++i)
        t[ty + i * 8][tx] = W[(size_t)(k0 + ty + i * 8) * DOUT + n0 + tx];
    __syncthreads();
#pragma unroll
    for (int i = 0; i < 4; ++i) {
        float v = t[tx][ty + i * 8];
        size_t o = (size_t)(n0 + ty + i * 8) * DIN + k0 + tx;
        unsigned hb = bf16_rn(v);
        wh[o] = (u16)hb;
        float r = v - __uint_as_float(hb << 16);
        wl[o] = (u16)bf16_rn(r);
    }
}

// ---------- MFMA GEMM: C = tanh(x@W + bias + probs), bf16x3 ----------
// 128x128 tile, 4 waves (2x2), each wave 4x4 tiles of 16x16x32, BK=32.
// v2.1: double-buffered LDS + single barrier per K-step (T3 "minimum 2-phase").
//     ds_read(cur) -> issue prefetch(next) -> MFMA -> __syncthreads (drain).
//     Prefetch is issued AFTER ds_reads so conservative LDS-alias analysis can
//     never force a vmcnt wait in front of the fragment reads.
//     Last iteration peeled: hot loop has unconditional prefetch, no branch.
// LDS per buffer 32KB: Ah[0,4096) Al[4096,8192) Bh[8192,12288) Bl[12288,16384)
// (u16 offsets). Rows of 32 bf16 (64B), XOR swizzle phys_quad = quad^((row>>1)&3).
__global__ __launch_bounds__(256, 2) void gemm_mfma_kernel(
    const u16* __restrict__ xh, const u16* __restrict__ xl,
    const u16* __restrict__ wh, const u16* __restrict__ wl,
    const float* __restrict__ bias, const float* __restrict__ probs,
    float* __restrict__ C)
{
    __shared__ u16 lds[2][16384];  // 64KB total -> 2 blocks/CU

    const int tid = threadIdx.x;
    const int lane = tid & 63;
    const int wave = tid >> 6;

    // T1: bijective XCD swizzle. 512 blocks, 512 % 8 == 0 -> simple form.
    // m-fastest within an XCD chunk: each XCD keeps 2 B-panels (2MB) L2-hot.
    const int bid = blockIdx.x;
    const int swz = (bid & 7) * 64 + (bid >> 3);
    const int bR = (swz & 31) * 128;
    const int bC = (swz >> 5) * 128;

    // Each wave DMAs one array (A_hi/A_lo/B_hi/B_lo), 8 chunks of 1KB.
    const u16* gsrc = (wave == 0) ? xh + (size_t)bR * DIN
                    : (wave == 1) ? xl + (size_t)bR * DIN
                    : (wave == 2) ? wh + (size_t)bC * DIN
                                  : wl + (size_t)bC * DIN;

    int goff[8];
#pragma unroll
    for (int i = 0; i < 8; ++i) {
        int row = i * 16 + (lane >> 2);
        int lq = (lane & 3) ^ ((row >> 1) & 3);  // pre-swizzled global source (rule #21)
        goff[i] = row * DIN + lq * 8;
    }

    const int wm = wave >> 1, wn = wave & 1;
    const int colL = lane & 15, quad = lane >> 4;

    int aoff[4], boff[4];
#pragma unroll
    for (int mt = 0; mt < 4; ++mt) {
        int r = wm * 64 + mt * 16 + colL;
        aoff[mt] = r * 32 + (quad ^ ((r >> 1) & 3)) * 8;          // A_hi region
    }
#pragma unroll
    for (int nt = 0; nt < 4; ++nt) {
        int r = wn * 64 + nt * 16 + colL;
        boff[nt] = 8192 + r * 32 + (quad ^ ((r >> 1) & 3)) * 8;   // B_hi region
    }

    u16* st0 = &lds[0][0] + wave * 4096;  // this wave's stage region, buf 0
    u16* st1 = st0 + 16384;               // same region, buf 1

    f32x4 acc[4][4];
#pragma unroll
    for (int mt = 0; mt < 4; ++mt)
#pragma unroll
        for (int nt = 0; nt < 4; ++nt) acc[mt][nt] = (f32x4){0.f, 0.f, 0.f, 0.f};

    // prologue: stage K-tile 0 into buf 0, drain, barrier
#pragma unroll
    for (int i = 0; i < 8; ++i) async16(st0 + i * 512, gsrc + goff[i]);
    __syncthreads();

#pragma unroll 2
    for (int t = 0; t < 63; ++t) {
        const int cur = t & 1;
        const u16* Lb = &lds[0][0] + cur * 16384;

        // 1) fragment reads from current buffer
        short8 ah[4], al[4], bh[4], bl[4];
#pragma unroll
        for (int mt = 0; mt < 4; ++mt) {
            ah[mt] = *(const short8*)(Lb + aoff[mt]);
            al[mt] = *(const short8*)(Lb + 4096 + aoff[mt]);
        }
#pragma unroll
        for (int nt = 0; nt < 4; ++nt) {
            bh[nt] = *(const short8*)(Lb + boff[nt]);
            bl[nt] = *(const short8*)(Lb + 4096 + boff[nt]);
        }

        // 2) issue next K-tile's DMA into the other buffer (overlaps with MFMA)
        {
            u16* st = cur ? st0 : st1;
            const int k1 = (t + 1) * 32;
#pragma unroll
            for (int i = 0; i < 8; ++i) async16(st + i * 512, gsrc + goff[i] + k1);
        }

        // 3) MFMA (bf16x3: hh + hl + lh)
#pragma unroll
        for (int mt = 0; mt < 4; ++mt)
#pragma unroll
            for (int nt = 0; nt < 4; ++nt) {
                acc[mt][nt] = __builtin_amdgcn_mfma_f32_16x16x32_bf16(
                    ah[mt], bh[nt], acc[mt][nt], 0, 0, 0);
                acc[mt][nt] = __builtin_amdgcn_mfma_f32_16x16x32_bf16(
                    ah[mt], bl[nt], acc[mt][nt], 0, 0, 0);
                acc[mt][nt] = __builtin_amdgcn_mfma_f32_16x16x32_bf16(
                    al[mt], bh[nt], acc[mt][nt], 0, 0, 0);
            }

        // 4) single barrier: drains this iteration's DMA (vmcnt) and all
        //    waves' frag reads before buffers swap roles.
        __syncthreads();
    }

    // peeled final K-step (t = 63, buf 1): no prefetch
    {
        const u16* Lb = &lds[0][0] + 16384;
        short8 ah[4], al[4], bh[4], bl[4];
#pragma unroll
        for (int mt = 0; mt < 4; ++mt) {
            ah[mt] = *(const short8*)(Lb + aoff[mt]);
            al[mt] = *(const short8*)(Lb + 4096 + aoff[mt]);
        }
#pragma unroll
        for (int nt = 0; nt < 4; ++nt) {
            bh[nt] = *(const short8*)(Lb + boff[nt]);
            bl[nt] = *(const short8*)(Lb + 4096 + boff[nt]);
        }
#pragma unroll
        for (int mt = 0; mt < 4; ++mt)
#pragma unroll
            for (int nt = 0; nt < 4; ++nt) {
                acc[mt][nt] = __builtin_amdgcn_mfma_f32_16x16x32_bf16(
                    ah[mt], bh[nt], acc[mt][nt], 0, 0, 0);
                acc[mt][nt] = __builtin_amdgcn_mfma_f32_16x16x32_bf16(
                    ah[mt], bl[nt], acc[mt][nt], 0, 0, 0);
                acc[mt][nt] = __builtin_amdgcn_mfma_f32_16x16x32_bf16(
                    al[mt], bh[nt], acc[mt][nt], 0, 0, 0);
            }
    }

    // epilogue: C/D map col=lane&15, row=quad*4+reg (verified m89/m91)
    float bp[4];
#pragma unroll
    for (int nt = 0; nt < 4; ++nt) {
        int c = bC + wn * 64 + nt * 16 + colL;
        bp[nt] = bias[c] + probs[c];
    }
#pragma unroll
    for (int mt = 0; mt < 4; ++mt)
#pragma unroll
        for (int nt = 0; nt < 4; ++nt) {
            int c = bC + wn * 64 + nt * 16 + colL;
#pragma unroll
            for (int reg = 0; reg < 4; ++reg) {
                int r = bR + wm * 64 + mt * 16 + quad * 4 + reg;
                C[(size_t)r * DOUT + c] = tanh_fast(acc[mt][nt][reg] + bp[nt]);
            }
        }
}

// ---------- fallback f32 GEMM (round-1, used if ws too small) ----------
__global__ __launch_bounds__(256) void gemm_tanh_kernel(
    const float* __restrict__ A, const float* __restrict__ Bw,
    const float* __restrict__ bias, const float* __restrict__ probs,
    float* __restrict__ C)
{
    __shared__ float As[16][128 + 4];
    __shared__ float Bs[16][128 + 4];
    const int tid = threadIdx.x;
    const int block_row = blockIdx.y * 128;
    const int block_col = blockIdx.x * 128;
    const int tr = (tid >> 4) << 3;
    const int tc = (tid & 15) << 3;
    const int a_row = tid >> 2;
    const int a_col = (tid & 3) << 2;
    const int b_row = tid >> 5;
    const int b_col = (tid & 31) << 2;
    const float* Aptr0 = A + (size_t)(block_row + a_row) * DIN + a_col;
    const float* Aptr1 = Aptr0 + (size_t)64 * DIN;
    const float* Bptr0 = Bw + (size_t)b_row * DOUT + block_col + b_col;
    const float* Bptr1 = Bptr0 + (size_t)8 * DOUT;
    float acc[8][8] = {};
    for (int k0 = 0; k0 < DIN; k0 += 16) {
        float4 a0 = *(const float4*)(Aptr0 + k0);
        float4 a1 = *(const float4*)(Aptr1 + k0);
        float4 b0 = *(const float4*)(Bptr0 + (size_t)k0 * DOUT);
        float4 b1 = *(const float4*)(Bptr1 + (size_t)k0 * DOUT);
        __syncthreads();
        As[a_col + 0][a_row] = a0.x;
        As[a_col + 1][a_row] = a0.y;
        As[a_col + 2][a_row] = a0.z;
        As[a_col + 3][a_row] = a0.w;
        As[a_col + 0][a_row + 64] = a1.x;
        As[a_col + 1][a_row + 64] = a1.y;
        As[a_col + 2][a_row + 64] = a1.z;
        As[a_col + 3][a_row + 64] = a1.w;
        *(float4*)&Bs[b_row][b_col]     = b0;
        *(float4*)&Bs[b_row + 8][b_col] = b1;
        __syncthreads();
#pragma unroll
        for (int kk = 0; kk < 16; ++kk) {
            float ar[8], br[8];
#pragma unroll
            for (int i = 0; i < 8; ++i) ar[i] = As[kk][tr + i];
#pragma unroll
            for (int i = 0; i < 8; ++i) br[i] = Bs[kk][tc + i];
#pragma unroll
            for (int i = 0; i < 8; ++i)
#pragma unroll
                for (int jj = 0; jj < 8; ++jj)
                    acc[i][jj] = fmaf(ar[i], br[jj], acc[i][jj]);
        }
    }
    float bp[8];
#pragma unroll
    for (int jj = 0; jj < 8; ++jj)
        bp[jj] = bias[block_col + tc + jj] + probs[block_col + tc + jj];
#pragma unroll
    for (int i = 0; i < 8; ++i) {
        float* crow = C + (size_t)(block_row + tr + i) * DOUT + block_col + tc;
#pragma unroll
        for (int jj = 0; jj < 8; ++jj)
            crow[jj] = tanh_fast(acc[i][jj] + bp[jj]);
    }
}

extern "C" void kernel_launch(void* const* d_in, const int* in_sizes, int n_in,
                              void* d_out, int out_size, void* d_ws, size_t ws_size,
                              hipStream_t stream) {
    const float* x  = (const float*)d_in[0];  // [4096, 2048]
    const float* W  = (const float*)d_in[1];  // [16, 2048, 2048]
    const float* cw = (const float*)d_in[2];  // [2048, 2048]
    const float* cb = (const float*)d_in[3];  // [2048]
    float* out = (float*)d_out;

    // ws layout: probs f32[2048] | x_hi | x_lo | wt_hi | wt_lo  (bf16 bits as u16)
    const size_t PROBS_B = 8192;
    const size_t XSZ = (size_t)BATCH * DIN;   // 8388608
    const size_t WSZ = (size_t)DIN * DOUT;    // 4194304
    const size_t need = PROBS_B + 2 * XSZ * 2 + 2 * WSZ * 2;  // 50,339,840 B

    float* probs = (float*)d_ws;
    probs_kernel<<<DOUT / 16, 256, 0, stream>>>(W, probs);

    if (ws_size >= need) {
        u16* xh = (u16*)((char*)d_ws + PROBS_B);
        u16* xl = xh + XSZ;
        u16* wh = xl + XSZ;
        u16* wl = wh + WSZ;

        convert_x_kernel<<<XSZ / 4 / 256, 256, 0, stream>>>(x, xh, xl);
        transpose_w_kernel<<<dim3(DOUT / 32, DIN / 32), 256, 0, stream>>>(cw, wh, wl);

        gemm_mfma_kernel<<<512, 256, 0, stream>>>(xh, xl, wh, wl, cb, probs, out);
    } else {
        dim3 grid(DOUT / 128, BATCH / 128);
        gemm_tanh_kernel<<<grid, 256, 0, stream>>>(x, cw, cb, probs, out);
    }
}